// Round 3
// baseline (175.071 us; speedup 1.0000x reference)
//
#include <hip/hip_runtime.h>
#include <hip/hip_bf16.h>

// ---------- types ----------
typedef __bf16 bf16x8 __attribute__((ext_vector_type(8)));
typedef float  floatx4 __attribute__((ext_vector_type(4)));

// ---------- helpers ----------
__device__ __forceinline__ __bf16 to_bf16(float f) {
    unsigned u = __builtin_bit_cast(unsigned, f);
    u += 0x7FFFu + ((u >> 16) & 1u);          // round-to-nearest-even
    unsigned short h = (unsigned short)(u >> 16);
    return __builtin_bit_cast(__bf16, h);
}

// Cayley sign for Cl(3,0): e_a * e_b = csign(a,b) * e_{a^b}
__host__ __device__ constexpr float csign(int a, int b) {
    int s = 0;
    for (int k = 1; k < 4; ++k) {
        int t = (a >> k) & b;
        s += (t & 1) + ((t >> 1) & 1) + ((t >> 2) & 1);
    }
    return (s & 1) ? -1.0f : 1.0f;
}

// rotor r: r[0]=scalar, r[1]=e12(idx3), r[2]=e13(idx5), r[3]=e23(idx6)
// x = r * s * reverse(r)
__device__ __forceinline__ void rotor_sandwich(const float r[4], const float s_in[8], float x[8]) {
    constexpr int RI[4] = {0, 3, 5, 6};
    float t[8];
#pragma unroll
    for (int k = 0; k < 8; ++k) t[k] = 0.f;
#pragma unroll
    for (int ia = 0; ia < 4; ++ia) {
#pragma unroll
        for (int jb = 0; jb < 8; ++jb) {
            t[RI[ia] ^ jb] += csign(RI[ia], jb) * r[ia] * s_in[jb];
        }
    }
    const float rr[4] = {r[0], -r[1], -r[2], -r[3]};
#pragma unroll
    for (int k = 0; k < 8; ++k) x[k] = 0.f;
#pragma unroll
    for (int ka = 0; ka < 8; ++ka) {
#pragma unroll
        for (int ib = 0; ib < 4; ++ib) {
            x[ka ^ RI[ib]] += csign(ka, RI[ib]) * t[ka] * rr[ib];
        }
    }
}

__device__ __forceinline__ void rotor_from_bv(float b0, float b1, float b2, float r[4]) {
    float t2 = b0 * b0 + b1 * b1 + b2 * b2;
    float th = sqrtf(t2);
    float sc = (th > 1e-6f) ? (__sinf(th) / th) : 1.0f;
    r[0] = __cosf(th);
    r[1] = sc * b0;
    r[2] = sc * b1;
    r[3] = sc * b2;
}

// Per-channel forward: sandwich -> norm -> gelu-gate -> channel sandwich.
__device__ __forceinline__ void channel_fwd(const float r[4], float nsc,
                                            const float* __restrict__ rbv,
                                            float4 s0, float4 s1,
                                            float* xo, float* hf) {
    float s_in[8] = {s0.x, s0.y, s0.z, s0.w, s1.x, s1.y, s1.z, s1.w};
    float xv[8];
    rotor_sandwich(r, s_in, xv);
    float ss = 1e-6f;
#pragma unroll
    for (int d = 0; d < 8; ++d) ss += xv[d] * xv[d];
    float hscale = nsc * rsqrtf(ss);
    float gate = 0.5f * (1.0f + erff(xv[0] * hscale * 0.70710678118654752440f));
    float g2 = hscale * gate;
    float hv[8];
#pragma unroll
    for (int d = 0; d < 8; ++d) hv[d] = xv[d] * g2;
    float rc[4];
    rotor_from_bv(-0.5f * rbv[0], -0.5f * rbv[1], -0.5f * rbv[2], rc);
    rotor_sandwich(rc, hv, hf);
#pragma unroll
    for (int d = 0; d < 8; ++d) xo[d] = xv[d];
}

// ---------- kernel ----------
// 256 threads = 4 independent waves, NO LDS, no barriers.
// Round-1-verified ownership & layouts, identity k-map throughout:
//   lane (bl=l&15, q=l>>4): owns b = base + bl, channels 8q..8q+7
//   A = h  : A[m=bl][k=8q+j] = h[b][c=8q+j]         (round-1 afrag)
//   B = W  : B[k=8q+j][n=bl] = W[o=bl+16hh][i=8q+j] (round-1 bfrag)
//   residual folded via identity MFMA: acc += x * I, where
//   B_I[k=8q+j][n=bl] = (8q+j == bl+16hh) ? 1 : 0
//   => acc[d][hh][rg] = next[b=base+4q+rg][o=bl+16hh][d]  (D-layout)
// d is the register index -> float4-of-d stores straight to global.
__global__ __launch_bounds__(256, 3) void dyn_kernel(
    const float* __restrict__ state, const int* __restrict__ action,
    const float* __restrict__ act_bv, const float* __restrict__ norm_scale,
    const float* __restrict__ rotor_bv, const float* __restrict__ lin_W,
    const float* __restrict__ lin_b, const float* __restrict__ reward_W,
    const float* __restrict__ reward_b,
    float* __restrict__ out_reward, float* __restrict__ out_next)
{
    const int tid   = threadIdx.x;
    const int lane  = tid & 63;
    const int wv    = tid >> 6;
    const int bl    = lane & 15;
    const int q     = lane >> 4;
    const int bbase = blockIdx.x * 64 + wv * 16;
    const int b     = bbase + bl;
    const int cbase = 8 * q;            // owned channels 8q..8q+7

    // ---- action rotor ----
    float r[4];
    {
        const int a = action[b];
        const float* p = act_bv + a * 3;
        rotor_from_bv(-0.5f * p[0], -0.5f * p[1], -0.5f * p[2], r);
    }

    // ---- phase A: 8 owned channels, pairwise; build A-fragments for h and x ----
    bf16x8 ah[8];   // ah[d][j]  = bf16(h_final[c=8q+j][d])
    bf16x8 ax[8];   // ax[d][j]  = bf16(x[c=8q+j][d])
    const float* sp = state + ((size_t)b * 32 + cbase) * 8;   // 256B contiguous
#pragma unroll
    for (int i = 0; i < 4; ++i) {
        const int cA = cbase + 2 * i, cB = cA + 1;
        float4 sa0 = ((const float4*)sp)[4 * i + 0];
        float4 sa1 = ((const float4*)sp)[4 * i + 1];
        float4 sb0 = ((const float4*)sp)[4 * i + 2];
        float4 sb1 = ((const float4*)sp)[4 * i + 3];
        float xa[8], ha[8], xb[8], hb[8];
        channel_fwd(r, norm_scale[cA], rotor_bv + cA * 3, sa0, sa1, xa, ha);
        channel_fwd(r, norm_scale[cB], rotor_bv + cB * 3, sb0, sb1, xb, hb);
#pragma unroll
        for (int d = 0; d < 8; ++d) {
            ah[d][2 * i]     = to_bf16(ha[d]);
            ah[d][2 * i + 1] = to_bf16(hb[d]);
            ax[d][2 * i]     = to_bf16(xa[d]);
            ax[d][2 * i + 1] = to_bf16(xb[d]);
        }
    }

    // ---- identity B-fragments (residual pass-through) ----
    const __bf16 one_bf  = __builtin_bit_cast(__bf16, (unsigned short)0x3F80);
    const __bf16 zero_bf = __builtin_bit_cast(__bf16, (unsigned short)0x0000);
    bf16x8 BI[2];
#pragma unroll
    for (int hh = 0; hh < 2; ++hh)
#pragma unroll
        for (int j = 0; j < 8; ++j)
            BI[hh][j] = (cbase + j == bl + 16 * hh) ? one_bf : zero_bf;

    // bias (d=0 only), per o-half; same value for all rg
    const float lb[2] = {lin_b[bl], lin_b[bl + 16]};

    constexpr int GR[8] = {0, 1, 1, 2, 1, 2, 2, 3};
    float r4[4] = {0.f, 0.f, 0.f, 0.f};   // reward partials per rg

    // ---- two d-passes: MFMA then direct D-layout stores (float4 of d) ----
#pragma unroll
    for (int pass = 0; pass < 2; ++pass) {
        // W B-fragments for the grades this pass needs (identity k-map, round-1 exact)
        bf16x8 Wf[4][2];
#pragma unroll
        for (int hh = 0; hh < 2; ++hh) {
            const int o = bl + 16 * hh;
#pragma unroll
            for (int j = 0; j < 8; ++j) {
                float4 w = ((const float4*)lin_W)[o * 32 + cbase + j];
                Wf[0][hh][j] = to_bf16(w.x);
                Wf[1][hh][j] = to_bf16(w.y);
                Wf[2][hh][j] = to_bf16(w.z);
                Wf[3][hh][j] = to_bf16(w.w);
            }
        }

        floatx4 acc[4][2];
#pragma unroll
        for (int dd = 0; dd < 4; ++dd) {
            const int d = pass * 4 + dd;
#pragma unroll
            for (int hh = 0; hh < 2; ++hh) {
                floatx4 c0;
                const float ci = (d == 0) ? lb[hh] : 0.f;
                c0[0] = ci; c0[1] = ci; c0[2] = ci; c0[3] = ci;
                floatx4 t = __builtin_amdgcn_mfma_f32_16x16x32_bf16(ah[d], Wf[GR[d]][hh], c0, 0, 0, 0);
                acc[dd][hh]  = __builtin_amdgcn_mfma_f32_16x16x32_bf16(ax[d], BI[hh],     t,  0, 0, 0);
            }
        }

        // reward partial from d=0 (pass 0 only)
        if (pass == 0) {
            const float rwlo = reward_W[bl], rwhi = reward_W[bl + 16];
#pragma unroll
            for (int rg = 0; rg < 4; ++rg)
                r4[rg] = acc[0][0][rg] * rwlo + acc[0][1][rg] * rwhi;
        }

        // stores: lane holds next[b=bbase+4q+rg][o=bl+16hh][d=pass*4..+3]
#pragma unroll
        for (int hh = 0; hh < 2; ++hh) {
#pragma unroll
            for (int rg = 0; rg < 4; ++rg) {
                float* dst = out_next +
                    ((size_t)(bbase + 4 * q + rg) * 32 + (bl + 16 * hh)) * 8 + 4 * pass;
                float4 v = {acc[0][hh][rg], acc[1][hh][rg], acc[2][hh][rg], acc[3][hh][rg]};
                *(float4*)dst = v;
            }
        }
    }

    // ---- reward: reduce over o (the 16 bl-lanes of this quad) ----
#pragma unroll
    for (int m = 1; m <= 8; m <<= 1) {
#pragma unroll
        for (int rg = 0; rg < 4; ++rg)
            r4[rg] += __shfl_xor(r4[rg], m, 64);
    }
    if (bl < 4) {
        float v = (bl == 0) ? r4[0] : (bl == 1) ? r4[1] : (bl == 2) ? r4[2] : r4[3];
        out_reward[bbase + 4 * q + bl] = v + reward_b[0];
    }
}

// ---------- launch ----------
extern "C" void kernel_launch(void* const* d_in, const int* in_sizes, int n_in,
                              void* d_out, int out_size, void* d_ws, size_t ws_size,
                              hipStream_t stream) {
    const float* state      = (const float*)d_in[0];
    const int*   action     = (const int*)  d_in[1];
    const float* act_bv     = (const float*)d_in[2];
    const float* norm_scale = (const float*)d_in[3];
    const float* rotor_bv   = (const float*)d_in[4];
    const float* lin_W      = (const float*)d_in[5];
    const float* lin_b      = (const float*)d_in[6];
    const float* reward_W   = (const float*)d_in[7];
    const float* reward_b   = (const float*)d_in[8];

    float* out = (float*)d_out;
    const int B = in_sizes[1];           // action: (B,)
    float* out_reward = out;             // (B,1) flattened
    float* out_next   = out + B;         // (B,32,8) flattened

    dim3 grid(B / 64), block(256);
    hipLaunchKernelGGL(dyn_kernel, grid, block, 0, stream,
                       state, action, act_bv, norm_scale, rotor_bv,
                       lin_W, lin_b, reward_W, reward_b, out_reward, out_next);
    (void)n_in; (void)out_size; (void)d_ws; (void)ws_size;
}

// Round 4
// 147.998 us; speedup vs baseline: 1.1829x; 1.1829x over previous
//
#include <hip/hip_runtime.h>
#include <hip/hip_bf16.h>

// ---------- types ----------
typedef __bf16 bf16x8 __attribute__((ext_vector_type(8)));
typedef float  floatx4 __attribute__((ext_vector_type(4)));

// ---------- helpers ----------
__device__ __forceinline__ __bf16 to_bf16(float f) {
    unsigned u = __builtin_bit_cast(unsigned, f);
    u += 0x7FFFu + ((u >> 16) & 1u);          // round-to-nearest-even
    unsigned short h = (unsigned short)(u >> 16);
    return __builtin_bit_cast(__bf16, h);
}

// Cayley sign for Cl(3,0): e_a * e_b = csign(a,b) * e_{a^b}
__host__ __device__ constexpr float csign(int a, int b) {
    int s = 0;
    for (int k = 1; k < 4; ++k) {
        int t = (a >> k) & b;
        s += (t & 1) + ((t >> 1) & 1) + ((t >> 2) & 1);
    }
    return (s & 1) ? -1.0f : 1.0f;
}

// rotor r: r[0]=scalar, r[1]=e12(idx3), r[2]=e13(idx5), r[3]=e23(idx6)
// x = r * s * reverse(r)
__device__ __forceinline__ void rotor_sandwich(const float r[4], const float s_in[8], float x[8]) {
    constexpr int RI[4] = {0, 3, 5, 6};
    float t[8];
#pragma unroll
    for (int k = 0; k < 8; ++k) t[k] = 0.f;
#pragma unroll
    for (int ia = 0; ia < 4; ++ia) {
#pragma unroll
        for (int jb = 0; jb < 8; ++jb) {
            t[RI[ia] ^ jb] += csign(RI[ia], jb) * r[ia] * s_in[jb];
        }
    }
    const float rr[4] = {r[0], -r[1], -r[2], -r[3]};
#pragma unroll
    for (int k = 0; k < 8; ++k) x[k] = 0.f;
#pragma unroll
    for (int ka = 0; ka < 8; ++ka) {
#pragma unroll
        for (int ib = 0; ib < 4; ++ib) {
            x[ka ^ RI[ib]] += csign(ka, RI[ib]) * t[ka] * rr[ib];
        }
    }
}

__device__ __forceinline__ void rotor_from_bv(float b0, float b1, float b2, float r[4]) {
    float t2 = b0 * b0 + b1 * b1 + b2 * b2;
    float th = sqrtf(t2);
    float sc = (th > 1e-6f) ? (__sinf(th) / th) : 1.0f;
    r[0] = __cosf(th);
    r[1] = sc * b0;
    r[2] = sc * b1;
    r[3] = sc * b2;
}

// Per-channel forward: sandwich -> norm -> gelu-gate -> channel sandwich.
__device__ __forceinline__ void channel_fwd(const float r[4], float nsc,
                                            const float* __restrict__ rbv,
                                            float4 s0, float4 s1,
                                            float* xo, float* hf) {
    float s_in[8] = {s0.x, s0.y, s0.z, s0.w, s1.x, s1.y, s1.z, s1.w};
    float xv[8];
    rotor_sandwich(r, s_in, xv);
    float ss = 1e-6f;
#pragma unroll
    for (int d = 0; d < 8; ++d) ss += xv[d] * xv[d];
    float hscale = nsc * rsqrtf(ss);
    float gate = 0.5f * (1.0f + erff(xv[0] * hscale * 0.70710678118654752440f));
    float g2 = hscale * gate;
    float hv[8];
#pragma unroll
    for (int d = 0; d < 8; ++d) hv[d] = xv[d] * g2;
    float rc[4];
    rotor_from_bv(-0.5f * rbv[0], -0.5f * rbv[1], -0.5f * rbv[2], rc);
    rotor_sandwich(rc, hv, hf);
#pragma unroll
    for (int d = 0; d < 8; ++d) xo[d] = xv[d];
}

// ---------- kernel ----------
// 256 threads = 4 independent waves, NO LDS, no barriers.
// Round-1/3-verified ownership & layouts, identity k-map:
//   lane (bl=l&15, q=l>>4): owns b = base + bl, channels 8q..8q+7
//   A = h : A[m=bl][k=8q+j] = h[b][c=8q+j]
//   B = W : B[k=8q+j][n=bl] = W[o=bl+16hh][i=8q+j]
//   residual folded via identity MFMA (B_I[k=8q+j][n=bl] = (8q+j==bl+16hh))
//   => lane holds next[b=base+4q+rg][o=bl+16hh][d] for rg=0..3, all 8 d.
// SINGLE pass over d (16 live accumulators) so the epilogue writes 32
// CONTIGUOUS bytes per lane per (hh,rg): one wave-instruction covers
// 4 rows x 512 B fully -> no partial-line write amplification (round-3 bug).
__global__ __launch_bounds__(256, 2) void dyn_kernel(
    const float* __restrict__ state, const int* __restrict__ action,
    const float* __restrict__ act_bv, const float* __restrict__ norm_scale,
    const float* __restrict__ rotor_bv, const float* __restrict__ lin_W,
    const float* __restrict__ lin_b, const float* __restrict__ reward_W,
    const float* __restrict__ reward_b,
    float* __restrict__ out_reward, float* __restrict__ out_next)
{
    const int tid   = threadIdx.x;
    const int lane  = tid & 63;
    const int wv    = tid >> 6;
    const int bl    = lane & 15;
    const int q     = lane >> 4;
    const int bbase = blockIdx.x * 64 + wv * 16;
    const int b     = bbase + bl;
    const int cbase = 8 * q;            // owned channels 8q..8q+7

    // ---- W fragments (hoisted: in flight during phase A), identity k-map ----
    bf16x8 Wf[4][2];
#pragma unroll
    for (int hh = 0; hh < 2; ++hh) {
        const int o = bl + 16 * hh;
#pragma unroll
        for (int j = 0; j < 8; ++j) {
            float4 w = ((const float4*)lin_W)[o * 32 + cbase + j];
            Wf[0][hh][j] = to_bf16(w.x);
            Wf[1][hh][j] = to_bf16(w.y);
            Wf[2][hh][j] = to_bf16(w.z);
            Wf[3][hh][j] = to_bf16(w.w);
        }
    }
    const float lb[2] = {lin_b[bl], lin_b[bl + 16]};
    const float rwlo = reward_W[bl], rwhi = reward_W[bl + 16];

    // ---- action rotor ----
    float r[4];
    {
        const int a = action[b];
        const float* p = act_bv + a * 3;
        rotor_from_bv(-0.5f * p[0], -0.5f * p[1], -0.5f * p[2], r);
    }

    // ---- phase A: 8 owned channels; build A-fragments for h and x ----
    bf16x8 ah[8];   // ah[d][j] = bf16(h_final[c=8q+j][d])
    bf16x8 ax[8];   // ax[d][j] = bf16(x[c=8q+j][d])
    const float* sp = state + ((size_t)b * 32 + cbase) * 8;   // 256B contiguous
#pragma unroll
    for (int i = 0; i < 4; ++i) {
        const int cA = cbase + 2 * i, cB = cA + 1;
        float4 sa0 = ((const float4*)sp)[4 * i + 0];
        float4 sa1 = ((const float4*)sp)[4 * i + 1];
        float4 sb0 = ((const float4*)sp)[4 * i + 2];
        float4 sb1 = ((const float4*)sp)[4 * i + 3];
        float xa[8], ha[8], xb[8], hb[8];
        channel_fwd(r, norm_scale[cA], rotor_bv + cA * 3, sa0, sa1, xa, ha);
        channel_fwd(r, norm_scale[cB], rotor_bv + cB * 3, sb0, sb1, xb, hb);
#pragma unroll
        for (int d = 0; d < 8; ++d) {
            ah[d][2 * i]     = to_bf16(ha[d]);
            ah[d][2 * i + 1] = to_bf16(hb[d]);
            ax[d][2 * i]     = to_bf16(xa[d]);
            ax[d][2 * i + 1] = to_bf16(xb[d]);
        }
    }

    // ---- identity B-fragments (residual pass-through) ----
    const __bf16 one_bf  = __builtin_bit_cast(__bf16, (unsigned short)0x3F80);
    const __bf16 zero_bf = __builtin_bit_cast(__bf16, (unsigned short)0x0000);
    bf16x8 BI[2];
#pragma unroll
    for (int hh = 0; hh < 2; ++hh)
#pragma unroll
        for (int j = 0; j < 8; ++j)
            BI[hh][j] = (cbase + j == bl + 16 * hh) ? one_bf : zero_bf;

    // ---- 16+16 MFMAs, all 8 d live ----
    constexpr int GR[8] = {0, 1, 1, 2, 1, 2, 2, 3};
    floatx4 acc[8][2];
#pragma unroll
    for (int d = 0; d < 8; ++d) {
#pragma unroll
        for (int hh = 0; hh < 2; ++hh) {
            floatx4 c0;
            const float ci = (d == 0) ? lb[hh] : 0.f;
            c0[0] = ci; c0[1] = ci; c0[2] = ci; c0[3] = ci;
            floatx4 t = __builtin_amdgcn_mfma_f32_16x16x32_bf16(ah[d], Wf[GR[d]][hh], c0, 0, 0, 0);
            acc[d][hh] = __builtin_amdgcn_mfma_f32_16x16x32_bf16(ax[d], BI[hh],       t,  0, 0, 0);
        }
    }

    // ---- stores: 32 contiguous bytes per lane per (hh,rg) ----
    // wave instruction = 4 rows x 512 B fully covered -> no partial lines
#pragma unroll
    for (int hh = 0; hh < 2; ++hh) {
#pragma unroll
        for (int rg = 0; rg < 4; ++rg) {
            float* dst = out_next +
                ((size_t)(bbase + 4 * q + rg) * 32 + (bl + 16 * hh)) * 8;
            float4 v0 = {acc[0][hh][rg], acc[1][hh][rg], acc[2][hh][rg], acc[3][hh][rg]};
            float4 v1 = {acc[4][hh][rg], acc[5][hh][rg], acc[6][hh][rg], acc[7][hh][rg]};
            ((float4*)dst)[0] = v0;
            ((float4*)dst)[1] = v1;
        }
    }

    // ---- reward: d=0 column, reduce over o (the 16 bl-lanes of this quad) ----
    float r4[4];
#pragma unroll
    for (int rg = 0; rg < 4; ++rg)
        r4[rg] = acc[0][0][rg] * rwlo + acc[0][1][rg] * rwhi;
#pragma unroll
    for (int m = 1; m <= 8; m <<= 1) {
#pragma unroll
        for (int rg = 0; rg < 4; ++rg)
            r4[rg] += __shfl_xor(r4[rg], m, 64);
    }
    if (bl < 4) {
        float v = (bl == 0) ? r4[0] : (bl == 1) ? r4[1] : (bl == 2) ? r4[2] : r4[3];
        out_reward[bbase + 4 * q + bl] = v + reward_b[0];
    }
}

// ---------- launch ----------
extern "C" void kernel_launch(void* const* d_in, const int* in_sizes, int n_in,
                              void* d_out, int out_size, void* d_ws, size_t ws_size,
                              hipStream_t stream) {
    const float* state      = (const float*)d_in[0];
    const int*   action     = (const int*)  d_in[1];
    const float* act_bv     = (const float*)d_in[2];
    const float* norm_scale = (const float*)d_in[3];
    const float* rotor_bv   = (const float*)d_in[4];
    const float* lin_W      = (const float*)d_in[5];
    const float* lin_b      = (const float*)d_in[6];
    const float* reward_W   = (const float*)d_in[7];
    const float* reward_b   = (const float*)d_in[8];

    float* out = (float*)d_out;
    const int B = in_sizes[1];           // action: (B,)
    float* out_reward = out;             // (B,1) flattened
    float* out_next   = out + B;         // (B,32,8) flattened

    dim3 grid(B / 64), block(256);
    hipLaunchKernelGGL(dyn_kernel, grid, block, 0, stream,
                       state, action, act_bv, norm_scale, rotor_bv,
                       lin_W, lin_b, reward_W, reward_b, out_reward, out_next);
    (void)n_in; (void)out_size; (void)d_ws; (void)ws_size;
}

// Round 6
// 142.204 us; speedup vs baseline: 1.2311x; 1.0407x over previous
//
#include <hip/hip_runtime.h>
#include <hip/hip_bf16.h>

// ---------- types ----------
typedef __bf16 bf16x8 __attribute__((ext_vector_type(8)));
typedef float  floatx4 __attribute__((ext_vector_type(4)));
typedef int    intx4   __attribute__((ext_vector_type(4)));

// ---------- precomputed tables (rebuilt every launch by build_tables) ----------
// g_Qc[c] = 3x3 rotation of channel-rotor sandwich, row-major Q11..Q33, padded to 12
__device__ __align__(16) float g_Qc[32][12];
// g_Wbf[g][hh][lane=16q+bl][j] = bf16(W[o=bl+16hh][c=8q+j][g])  (round-4 Wf layout)
__device__ __align__(16) unsigned short g_Wbf[4 * 2 * 64 * 8];

// ---------- helpers ----------
__device__ __forceinline__ unsigned bf16_bits_rne(float f) {
    unsigned u = __builtin_bit_cast(unsigned, f);
    u += 0x7FFFu + ((u >> 16) & 1u);
    return u;
}
// round-half-up pack: lo -> bits[15:0], hi -> bits[31:16]; 3 ops via v_perm
__device__ __forceinline__ int pack2(float lo, float hi) {
    unsigned ul = __builtin_bit_cast(unsigned, lo) + 0x8000u;
    unsigned uh = __builtin_bit_cast(unsigned, hi) + 0x8000u;
    return (int)__builtin_amdgcn_perm(uh, ul, 0x07060302u);
}

__device__ __forceinline__ void rotor_from_bv(float b0, float b1, float b2, float r[4]) {
    float t2 = b0 * b0 + b1 * b1 + b2 * b2;
    float th = sqrtf(t2);
    float sc = (th > 1e-6f) ? (__sinf(th) / th) : 1.0f;
    r[0] = __cosf(th);
    r[1] = sc * b0;
    r[2] = sc * b1;
    r[3] = sc * b2;
}

// Rotation matrix of the sandwich R v R~ on vectors (e1,e2,e3), rotor
// r = w + a e12 + b e13 + c e23.  Hand-derived & checked against direct
// Clifford products for columns e1,e2,e3 and bivector cases e12/e13/e23.
__device__ __forceinline__ void q_from_rotor(const float r[4], float Q[9]) {
    const float w = r[0], a = r[1], b = r[2], c = r[3];
    const float ww = w * w, aa = a * a, bb = b * b, cc = c * c;
    Q[0] = ww - aa - bb + cc;        // Q11
    Q[1] = 2.f * (w * a - b * c);    // Q12
    Q[2] = 2.f * (w * b + a * c);    // Q13
    Q[3] = -2.f * (w * a + b * c);   // Q21
    Q[4] = ww - aa + bb - cc;        // Q22
    Q[5] = 2.f * (w * c - a * b);    // Q23
    Q[6] = 2.f * (a * c - w * b);    // Q31
    Q[7] = -2.f * (w * c + a * b);   // Q32
    Q[8] = ww + aa - bb - cc;        // Q33
}

// Grade-block sandwich apply: out = (1 (+) Q (+) Qdual (+) 1) * s.
// Multivector index map: s[1],s[2],s[4] = e1,e2,e3 ; s[3],s[5],s[6] = e12,e13,e23.
// Bivector block from duality e12=I e3, e13=-I e2, e23=I e1 (verified cases).
__device__ __forceinline__ void qapply(const float Q[9], const float s[8], float o[8]) {
    o[0] = s[0];
    o[1] = Q[0] * s[1] + Q[1] * s[2] + Q[2] * s[4];
    o[2] = Q[3] * s[1] + Q[4] * s[2] + Q[5] * s[4];
    o[4] = Q[6] * s[1] + Q[7] * s[2] + Q[8] * s[4];
    o[3] = Q[8] * s[3] - Q[7] * s[5] + Q[6] * s[6];
    o[5] = -Q[5] * s[3] + Q[4] * s[5] - Q[3] * s[6];
    o[6] = Q[2] * s[3] - Q[1] * s[5] + Q[0] * s[6];
    o[7] = s[7];
}

// Per-channel forward: action-rotation -> norm -> gelu-gate -> channel-rotation.
// hf = Qc_apply(g2 * x) = g2 * Qc_apply(x)   (scalar commutes)
__device__ __forceinline__ void chan(const float QR[9], const float Qc[9], float nsc,
                                     float4 s0, float4 s1, float x[8], float hf[8]) {
    float s[8] = {s0.x, s0.y, s0.z, s0.w, s1.x, s1.y, s1.z, s1.w};
    qapply(QR, s, x);
    float ss = 1e-6f;
#pragma unroll
    for (int d = 0; d < 8; ++d) ss += x[d] * x[d];
    const float hs = nsc * rsqrtf(ss);
    const float gate = 0.5f * (1.0f + erff(x[0] * hs * 0.70710678118654752440f));
    const float g2 = hs * gate;
    float y[8];
    qapply(Qc, x, y);
#pragma unroll
    for (int d = 0; d < 8; ++d) hf[d] = y[d] * g2;
}

// ---------- setup kernel ----------
__global__ void build_tables(const float* __restrict__ rotor_bv,
                             const float* __restrict__ lin_W) {
    const int t = threadIdx.x;          // 0..255
    if (t < 32) {
        float r[4];
        rotor_from_bv(-0.5f * rotor_bv[3 * t], -0.5f * rotor_bv[3 * t + 1],
                      -0.5f * rotor_bv[3 * t + 2], r);
        float Q[9];
        q_from_rotor(r, Q);
#pragma unroll
        for (int k = 0; k < 9; ++k) g_Qc[t][k] = Q[k];
        g_Qc[t][9] = 0.f; g_Qc[t][10] = 0.f; g_Qc[t][11] = 0.f;
    }
#pragma unroll
    for (int i = 0; i < 16; ++i) {
        const int idx = t * 16 + i;                  // 0..4095
        const int j = idx & 7, lane = (idx >> 3) & 63;
        const int hh = (idx >> 9) & 1, g = idx >> 10;
        const int bl = lane & 15, q = lane >> 4;
        g_Wbf[idx] = (unsigned short)(
            bf16_bits_rne(lin_W[((bl + 16 * hh) * 32 + 8 * q + j) * 4 + g]) >> 16);
    }
}

// ---------- main kernel ----------
// 256 threads = 4 independent waves, NO LDS, no barriers.
// Round-4-VERIFIED dataflow (unchanged): lane (bl=l&15, q=l>>4) owns
// b = base+bl, channels 8q..8q+7; A=h fragments ah[d][j]=hf[c=8q+j][d];
// B=W fragments from g_Wbf (identity k-map); residual x folded via identity
// MFMA; lane ends holding next[b=base+4q+rg][o=bl+16hh][d] -> 32 B/lane stores.
// Only phase-A internals changed: grade-block Q-apply instead of 64-FMA sandwich.
__global__ __launch_bounds__(256, 2) void dyn_kernel(
    const float* __restrict__ state, const int* __restrict__ action,
    const float* __restrict__ act_bv, const float* __restrict__ norm_scale,
    const float* __restrict__ lin_b, const float* __restrict__ reward_W,
    const float* __restrict__ reward_b,
    float* __restrict__ out_reward, float* __restrict__ out_next)
{
    const int tid   = threadIdx.x;
    const int lane  = tid & 63;
    const int wv    = tid >> 6;
    const int bl    = lane & 15;
    const int q     = lane >> 4;
    const int bbase = blockIdx.x * 64 + wv * 16;
    const int b     = bbase + bl;
    const int cbase = 8 * q;

    // ---- state loads first (256B contiguous per lane) ----
    const float* sp = state + ((size_t)b * 32 + cbase) * 8;
    float4 sv[16];
#pragma unroll
    for (int k = 0; k < 16; ++k) sv[k] = ((const float4*)sp)[k];

    // ---- W fragments from prebuilt bf16 table (round-4 Wf layout) ----
    bf16x8 Wf[4][2];
#pragma unroll
    for (int g = 0; g < 4; ++g)
#pragma unroll
        for (int hh = 0; hh < 2; ++hh)
            Wf[g][hh] = ((const bf16x8*)g_Wbf)[(g * 2 + hh) * 64 + lane];

    const float lb[2] = {lin_b[bl], lin_b[bl + 16]};
    const float rw[2] = {reward_W[bl], reward_W[bl + 16]};

    // ---- action rotation matrix (per lane) ----
    float QR[9];
    {
        const int a = action[b];
        const float* p = act_bv + a * 3;
        float r[4];
        rotor_from_bv(-0.5f * p[0], -0.5f * p[1], -0.5f * p[2], r);
        q_from_rotor(r, QR);
    }

    // ---- phase A: 8 owned channels in pairs; pack A-fragments via v_perm ----
    int ahw[8][4];   // ah word i of ah[d]  (channels cbase+2i, +2i+1)
    int axw[8][4];   // ax word i of ax[d]
#pragma unroll
    for (int i = 0; i < 4; ++i) {
        const int cA = cbase + 2 * i, cB = cA + 1;
        float QcA[9], QcB[9];
        {
            const float4* qa = (const float4*)g_Qc[cA];
            const float4* qb = (const float4*)g_Qc[cB];
            float4 a0 = qa[0], a1 = qa[1], a2 = qa[2];
            float4 b0 = qb[0], b1 = qb[1], b2 = qb[2];
            QcA[0]=a0.x; QcA[1]=a0.y; QcA[2]=a0.z; QcA[3]=a0.w;
            QcA[4]=a1.x; QcA[5]=a1.y; QcA[6]=a1.z; QcA[7]=a1.w; QcA[8]=a2.x;
            QcB[0]=b0.x; QcB[1]=b0.y; QcB[2]=b0.z; QcB[3]=b0.w;
            QcB[4]=b1.x; QcB[5]=b1.y; QcB[6]=b1.z; QcB[7]=b1.w; QcB[8]=b2.x;
        }
        float xa[8], ha[8], xb[8], hb[8];
        chan(QR, QcA, norm_scale[cA], sv[4 * i + 0], sv[4 * i + 1], xa, ha);
        chan(QR, QcB, norm_scale[cB], sv[4 * i + 2], sv[4 * i + 3], xb, hb);
#pragma unroll
        for (int d = 0; d < 8; ++d) {
            ahw[d][i] = pack2(ha[d], hb[d]);
            axw[d][i] = pack2(xa[d], xb[d]);
        }
    }

    // ---- identity B-fragments (residual pass-through), round-4 verified ----
    const __bf16 one_bf  = __builtin_bit_cast(__bf16, (unsigned short)0x3F80);
    const __bf16 zero_bf = __builtin_bit_cast(__bf16, (unsigned short)0x0000);
    bf16x8 BI[2];
#pragma unroll
    for (int hh = 0; hh < 2; ++hh)
#pragma unroll
        for (int j = 0; j < 8; ++j)
            BI[hh][j] = (cbase + j == bl + 16 * hh) ? one_bf : zero_bf;

    // ---- 16+16 MFMAs, all 8 d live (round-4 verbatim) ----
    constexpr int GR[8] = {0, 1, 1, 2, 1, 2, 2, 3};
    floatx4 acc[8][2];
#pragma unroll
    for (int d = 0; d < 8; ++d) {
        intx4 aw = {ahw[d][0], ahw[d][1], ahw[d][2], ahw[d][3]};
        intx4 xw = {axw[d][0], axw[d][1], axw[d][2], axw[d][3]};
        bf16x8 ah = __builtin_bit_cast(bf16x8, aw);
        bf16x8 ax = __builtin_bit_cast(bf16x8, xw);
#pragma unroll
        for (int hh = 0; hh < 2; ++hh) {
            floatx4 c0;
            const float ci = (d == 0) ? lb[hh] : 0.f;
            c0[0] = ci; c0[1] = ci; c0[2] = ci; c0[3] = ci;
            floatx4 t = __builtin_amdgcn_mfma_f32_16x16x32_bf16(ah, Wf[GR[d]][hh], c0, 0, 0, 0);
            acc[d][hh] = __builtin_amdgcn_mfma_f32_16x16x32_bf16(ax, BI[hh],       t,  0, 0, 0);
        }
    }

    // ---- stores: 32 contiguous bytes per lane per (hh,rg) (round-4 verbatim) ----
#pragma unroll
    for (int hh = 0; hh < 2; ++hh) {
#pragma unroll
        for (int rg = 0; rg < 4; ++rg) {
            float* dst = out_next +
                ((size_t)(bbase + 4 * q + rg) * 32 + (bl + 16 * hh)) * 8;
            float4 v0 = {acc[0][hh][rg], acc[1][hh][rg], acc[2][hh][rg], acc[3][hh][rg]};
            float4 v1 = {acc[4][hh][rg], acc[5][hh][rg], acc[6][hh][rg], acc[7][hh][rg]};
            ((float4*)dst)[0] = v0;
            ((float4*)dst)[1] = v1;
        }
    }

    // ---- reward (round-4 verbatim) ----
    float r4[4];
#pragma unroll
    for (int rg = 0; rg < 4; ++rg)
        r4[rg] = acc[0][0][rg] * rw[0] + acc[0][1][rg] * rw[1];
#pragma unroll
    for (int m = 1; m <= 8; m <<= 1) {
#pragma unroll
        for (int rg = 0; rg < 4; ++rg)
            r4[rg] += __shfl_xor(r4[rg], m, 64);
    }
    if (bl < 4) {
        float v = (bl == 0) ? r4[0] : (bl == 1) ? r4[1] : (bl == 2) ? r4[2] : r4[3];
        out_reward[bbase + 4 * q + bl] = v + reward_b[0];
    }
}

// ---------- launch ----------
extern "C" void kernel_launch(void* const* d_in, const int* in_sizes, int n_in,
                              void* d_out, int out_size, void* d_ws, size_t ws_size,
                              hipStream_t stream) {
    const float* state      = (const float*)d_in[0];
    const int*   action     = (const int*)  d_in[1];
    const float* act_bv     = (const float*)d_in[2];
    const float* norm_scale = (const float*)d_in[3];
    const float* rotor_bv   = (const float*)d_in[4];
    const float* lin_W      = (const float*)d_in[5];
    const float* lin_b      = (const float*)d_in[6];
    const float* reward_W   = (const float*)d_in[7];
    const float* reward_b   = (const float*)d_in[8];

    float* out = (float*)d_out;
    const int B = in_sizes[1];           // action: (B,)
    float* out_reward = out;             // (B,1) flattened
    float* out_next   = out + B;         // (B,32,8) flattened

    hipLaunchKernelGGL(build_tables, dim3(1), dim3(256), 0, stream, rotor_bv, lin_W);
    hipLaunchKernelGGL(dyn_kernel, dim3(B / 64), dim3(256), 0, stream,
                       state, action, act_bv, norm_scale,
                       lin_b, reward_W, reward_b, out_reward, out_next);
    (void)n_in; (void)out_size; (void)d_ws; (void)ws_size;
}